// Round 1
// baseline (1664.861 us; speedup 1.0000x reference)
//
#include <hip/hip_runtime.h>

#define B_SZ   65536
#define IN_SZ  256
#define H_SZ   512
#define K_SZ   768          // IN + H
#define BM     64           // rows per block; each block does ALL 1024 output cols
#define BK     64
#define LDK    72           // padded LDS K-stride (bf16 elems); 144 B rows, 16B aligned
#define NCHUNK (K_SZ / BK)  // 12

typedef __attribute__((ext_vector_type(4))) float          f32x4;
typedef __attribute__((ext_vector_type(8))) __bf16         bf16x8;
typedef __attribute__((ext_vector_type(4))) unsigned short u16x4;

__device__ __forceinline__ unsigned short f2bf(float f) {
    unsigned u = __float_as_uint(f);
    u += 0x7FFFu + ((u >> 16) & 1u);      // round-to-nearest-even
    return (unsigned short)(u >> 16);
}

__device__ __forceinline__ float tanh_fast(float x) {
    x = fminf(fmaxf(x, -16.0f), 16.0f);
    float e = __expf(2.0f * x);
    return (e - 1.0f) / (e + 1.0f);
}

// Build Wt[1024][768] bf16, k-major: rows 0..511 = f-set cols, 512..1023 = c-set cols.
__global__ void prep_weights(const float* __restrict__ w_f, const float* __restrict__ w_c,
                             const float* __restrict__ r_f, const float* __restrict__ r_c,
                             unsigned short* __restrict__ wt) {
    int id = blockIdx.x * 256 + threadIdx.x;
    int n  = id / K_SZ;
    int k  = id - n * K_SZ;
    int col = n & (H_SZ - 1);
    float v;
    if (n < H_SZ) v = (k < IN_SZ) ? w_f[k * H_SZ + col] : r_f[(k - IN_SZ) * H_SZ + col];
    else          v = (k < IN_SZ) ? w_c[k * H_SZ + col] : r_c[(k - IN_SZ) * H_SZ + col];
    wt[(size_t)n * K_SZ + k] = f2bf(v);
}

// One block = 64 rows x full H (1024 output cols incl. F/C sets).
// 8 waves; wave w owns H-cols [w*64, w*64+64) with BOTH accF (4x4 frags) and accC.
// A staged in LDS (double-buffered, bf16-converted); weights read directly from
// global (L2-resident 1.5 MB). Epilogue re-layouts acc through a per-wave-private
// LDS slice so all global loads/stores are f32x4 over fully-written 256B rows.
__launch_bounds__(512, 2)
__global__ void smgu_kernel(const float* __restrict__ x, const float* __restrict__ h_prev,
                            const float* __restrict__ c_prev, const float* __restrict__ n_prev,
                            const float* __restrict__ m_prev,
                            const float* __restrict__ b_f, const float* __restrict__ b_c,
                            const unsigned short* __restrict__ wt,
                            float* __restrict__ out) {
    // union: K-loop uses sA [2][BM][LDK] bf16 = 18432 B; epilogue uses 8 x 8 KB f32 = 65536 B
    __shared__ __align__(16) unsigned char smem[65536];
    unsigned short* sA = (unsigned short*)smem;
    float*          eW = (float*)smem;

    const int tid  = threadIdx.x;
    const int m0   = blockIdx.x * BM;
    const int lane = tid & 63;
    const int wave = tid >> 6;            // 0..7 -> H-col group
    const int n0   = wave * 64;
    const int fr   = lane & 15;
    const int fg   = (lane >> 4) * 8;     // k-octet offset
    const int g    = lane >> 4;

    f32x4 accF[4][4], accC[4][4];
#pragma unroll
    for (int i = 0; i < 4; ++i)
#pragma unroll
        for (int j = 0; j < 4; ++j) { accF[i][j] = (f32x4)0.0f; accC[i][j] = (f32x4)0.0f; }

    // staging map: 1024 float4 chunks (64 rows x 16), thread does chunks tid and tid+512
    const int r0s = tid >> 4;             // 0..31
    const int c4s = tid & 15;

    f32x4 pv0, pv1;
    auto load_chunk = [&](int kb) {
        const float* src; int ld, kl;
        if (kb < IN_SZ) { src = x;      ld = IN_SZ; kl = kb; }
        else            { src = h_prev; ld = H_SZ;  kl = kb - IN_SZ; }
        pv0 = __builtin_nontemporal_load(
            (const f32x4*)&src[(size_t)(m0 + r0s) * ld + kl + c4s * 4]);
        pv1 = __builtin_nontemporal_load(
            (const f32x4*)&src[(size_t)(m0 + 32 + r0s) * ld + kl + c4s * 4]);
    };
    auto write_chunk = [&](int buf) {
        u16x4 w0, w1;
        w0[0] = f2bf(pv0[0]); w0[1] = f2bf(pv0[1]); w0[2] = f2bf(pv0[2]); w0[3] = f2bf(pv0[3]);
        w1[0] = f2bf(pv1[0]); w1[1] = f2bf(pv1[1]); w1[2] = f2bf(pv1[2]); w1[3] = f2bf(pv1[3]);
        *(u16x4*)&sA[(buf * BM + r0s) * LDK + c4s * 4]      = w0;
        *(u16x4*)&sA[(buf * BM + 32 + r0s) * LDK + c4s * 4] = w1;
    };

    load_chunk(0);
    write_chunk(0);
    __syncthreads();

    for (int t = 0; t < NCHUNK; ++t) {
        const int cur = t & 1;
        if (t + 1 < NCHUNK) load_chunk((t + 1) * BK);   // HBM latency hides under MFMAs
        const unsigned short* sAc = &sA[cur * BM * LDK];
#pragma unroll
        for (int ks = 0; ks < BK; ks += 32) {
            bf16x8 af[4], bfx[4], bcx[4];
#pragma unroll
            for (int mi = 0; mi < 4; ++mi)
                af[mi] = *(const bf16x8*)&sAc[(mi * 16 + fr) * LDK + ks + fg];
            const int kk = t * BK + ks + fg;
#pragma unroll
            for (int ni = 0; ni < 4; ++ni) {
                const int nr = n0 + ni * 16 + fr;
                bfx[ni] = *(const bf16x8*)&wt[(size_t)nr * K_SZ + kk];            // L2 hit
                bcx[ni] = *(const bf16x8*)&wt[(size_t)(H_SZ + nr) * K_SZ + kk];   // L2 hit
            }
#pragma unroll
            for (int mi = 0; mi < 4; ++mi)
#pragma unroll
                for (int ni = 0; ni < 4; ++ni) {
                    accF[mi][ni] = __builtin_amdgcn_mfma_f32_16x16x32_bf16(af[mi], bfx[ni], accF[mi][ni], 0, 0, 0);
                    accC[mi][ni] = __builtin_amdgcn_mfma_f32_16x16x32_bf16(af[mi], bcx[ni], accC[mi][ni], 0, 0, 0);
                }
        }
        if (t + 1 < NCHUNK) write_chunk(cur ^ 1);
        __syncthreads();   // also fences LDS before epilogue reuse on last iter
    }

    // ---- epilogue: per-wave-private LDS slice (no barriers), then pure f32x4 streaming.
    // C/D layout: col = lane&15, row = (lane>>4)*4 + reg  [m89/m91-verified]
    float* ef = eW + wave * 2048;   // [16][64] F slice
    float* ec = ef + 1024;          // [16][64] C slice
    const f32x4 bfv = *(const f32x4*)&b_f[n0 + fr * 4];
    const f32x4 bcv = *(const f32x4*)&b_c[n0 + fr * 4];
    const size_t BH = (size_t)B_SZ * H_SZ;

#pragma unroll 1
    for (int mi = 0; mi < 4; ++mi) {
#pragma unroll
        for (int ni = 0; ni < 4; ++ni)
#pragma unroll
            for (int r = 0; r < 4; ++r) {
                const int ri = g * 4 + r;
                const int cc = ni * 16 + fr;
                ef[ri * 64 + cc] = accF[mi][ni][r];
                ec[ri * 64 + cc] = accC[mi][ni][r];
            }
        // same-wave DS ordering: compiler inserts lgkmcnt wait before reads below
#pragma unroll
        for (int rr = 0; rr < 4; ++rr) {
            const int ri = rr * 4 + g;
            const size_t idx = (size_t)(m0 + mi * 16 + ri) * H_SZ + n0 + fr * 4;
            f32x4 pF = *(const f32x4*)&ef[ri * 64 + fr * 4];
            f32x4 pC = *(const f32x4*)&ec[ri * 64 + fr * 4];
            f32x4 cp = __builtin_nontemporal_load((const f32x4*)&c_prev[idx]);
            f32x4 np = __builtin_nontemporal_load((const f32x4*)&n_prev[idx]);
            f32x4 mp = __builtin_nontemporal_load((const f32x4*)&m_prev[idx]);
            f32x4 ho, co, no, mo;
#pragma unroll
            for (int q = 0; q < 4; ++q) {
                float preF = pF[q] + bfv[q];
                float s    = preF + mp[q];
                float mt   = fmaxf(s, 0.0f);
                float ipv  = __expf(-mt);
                float fpv  = __expf(s - mt);
                float ct   = fpv * cp[q] + ipv * tanh_fast(pC[q] + bcv[q]);
                float ntv  = fpv * np[q] + ipv;
                float htv  = tanh_fast(ct / fmaxf(ntv, 1e-8f));
                ho[q] = htv; co[q] = ct; no[q] = ntv; mo[q] = mt;
            }
            __builtin_nontemporal_store(ho, (f32x4*)&out[idx]);
            __builtin_nontemporal_store(co, (f32x4*)&out[BH + idx]);
            __builtin_nontemporal_store(no, (f32x4*)&out[2 * BH + idx]);
            __builtin_nontemporal_store(mo, (f32x4*)&out[3 * BH + idx]);
        }
    }
}

extern "C" void kernel_launch(void* const* d_in, const int* in_sizes, int n_in,
                              void* d_out, int out_size, void* d_ws, size_t ws_size,
                              hipStream_t stream) {
    const float* x      = (const float*)d_in[0];
    const float* h_prev = (const float*)d_in[1];
    const float* c_prev = (const float*)d_in[2];
    const float* n_prev = (const float*)d_in[3];
    const float* m_prev = (const float*)d_in[4];
    const float* w_f    = (const float*)d_in[5];
    const float* w_c    = (const float*)d_in[6];
    const float* r_f    = (const float*)d_in[7];
    const float* r_c    = (const float*)d_in[8];
    const float* b_f    = (const float*)d_in[9];
    const float* b_c    = (const float*)d_in[10];
    float* out = (float*)d_out;
    unsigned short* wt = (unsigned short*)d_ws;   // 1024*768*2 = 1.5 MiB

    prep_weights<<<(2 * H_SZ * K_SZ) / 256, 256, 0, stream>>>(w_f, w_c, r_f, r_c, wt);
    smgu_kernel<<<B_SZ / BM, 512, 0, stream>>>(
        x, h_prev, c_prev, n_prev, m_prev, b_f, b_c, wt, out);
}

// Round 2
// 1663.149 us; speedup vs baseline: 1.0010x; 1.0010x over previous
//
#include <hip/hip_runtime.h>

#define B_SZ   65536
#define IN_SZ  256
#define H_SZ   512
#define K_SZ   768          // IN + H
#define BM     64           // rows per block; each block does ALL 1024 output cols
#define BK     64
#define LDK    72           // padded LDS K-stride (bf16 elems); 144 B rows, 16B aligned
#define NCHUNK (K_SZ / BK)  // 12

typedef __attribute__((ext_vector_type(4))) float          f32x4;
typedef __attribute__((ext_vector_type(8))) __bf16         bf16x8;
typedef __attribute__((ext_vector_type(4))) unsigned short u16x4;

__device__ __forceinline__ unsigned short f2bf(float f) {
    unsigned u = __float_as_uint(f);
    u += 0x7FFFu + ((u >> 16) & 1u);      // round-to-nearest-even
    return (unsigned short)(u >> 16);
}

__device__ __forceinline__ float tanh_fast(float x) {
    x = fminf(fmaxf(x, -16.0f), 16.0f);
    float e = __expf(2.0f * x);
    return (e - 1.0f) / (e + 1.0f);
}

// Build Wt[1024][768] bf16, k-major: rows 0..511 = f-set cols, 512..1023 = c-set cols.
__global__ void prep_weights(const float* __restrict__ w_f, const float* __restrict__ w_c,
                             const float* __restrict__ r_f, const float* __restrict__ r_c,
                             unsigned short* __restrict__ wt) {
    int id = blockIdx.x * 256 + threadIdx.x;
    int n  = id / K_SZ;
    int k  = id - n * K_SZ;
    int col = n & (H_SZ - 1);
    float v;
    if (n < H_SZ) v = (k < IN_SZ) ? w_f[k * H_SZ + col] : r_f[(k - IN_SZ) * H_SZ + col];
    else          v = (k < IN_SZ) ? w_c[k * H_SZ + col] : r_c[(k - IN_SZ) * H_SZ + col];
    wt[(size_t)n * K_SZ + k] = f2bf(v);
}

// One block = 64 rows x full H (1024 output cols incl. F/C sets).
// 8 waves; wave w owns H-cols [w*64, w*64+64) with BOTH accF (4x4 frags) and accC.
// A staged in LDS (double-buffered, bf16-converted); weights read directly from
// global (L2-resident 1.5 MB, kept hot because streaming loads are nt/no-allocate).
// Epilogue re-layouts acc through a per-wave-private LDS slice so all global
// loads/stores are f32x4 over fully-written, 256B-contiguous aligned segments.
// NOTE: stores are PLAIN (not nontemporal) — nt stores bypass L2 write-combining
// on gfx950 and amplified WRITE_SIZE 7.3x (3.94 GB vs 537 MB ideal) in round 1.
__launch_bounds__(512, 2)
__global__ void smgu_kernel(const float* __restrict__ x, const float* __restrict__ h_prev,
                            const float* __restrict__ c_prev, const float* __restrict__ n_prev,
                            const float* __restrict__ m_prev,
                            const float* __restrict__ b_f, const float* __restrict__ b_c,
                            const unsigned short* __restrict__ wt,
                            float* __restrict__ out) {
    // union: K-loop uses sA [2][BM][LDK] bf16 = 18432 B; epilogue uses 8 x 8 KB f32 = 65536 B
    __shared__ __align__(16) unsigned char smem[65536];
    unsigned short* sA = (unsigned short*)smem;
    float*          eW = (float*)smem;

    const int tid  = threadIdx.x;
    const int m0   = blockIdx.x * BM;
    const int lane = tid & 63;
    const int wave = tid >> 6;            // 0..7 -> H-col group
    const int n0   = wave * 64;
    const int fr   = lane & 15;
    const int fg   = (lane >> 4) * 8;     // k-octet offset
    const int g    = lane >> 4;

    f32x4 accF[4][4], accC[4][4];
#pragma unroll
    for (int i = 0; i < 4; ++i)
#pragma unroll
        for (int j = 0; j < 4; ++j) { accF[i][j] = (f32x4)0.0f; accC[i][j] = (f32x4)0.0f; }

    // staging map: 1024 float4 chunks (64 rows x 16), thread does chunks tid and tid+512
    const int r0s = tid >> 4;             // 0..31
    const int c4s = tid & 15;

    f32x4 pv0, pv1;
    auto load_chunk = [&](int kb) {
        const float* src; int ld, kl;
        if (kb < IN_SZ) { src = x;      ld = IN_SZ; kl = kb; }
        else            { src = h_prev; ld = H_SZ;  kl = kb - IN_SZ; }
        pv0 = __builtin_nontemporal_load(
            (const f32x4*)&src[(size_t)(m0 + r0s) * ld + kl + c4s * 4]);
        pv1 = __builtin_nontemporal_load(
            (const f32x4*)&src[(size_t)(m0 + 32 + r0s) * ld + kl + c4s * 4]);
    };
    auto write_chunk = [&](int buf) {
        u16x4 w0, w1;
        w0[0] = f2bf(pv0[0]); w0[1] = f2bf(pv0[1]); w0[2] = f2bf(pv0[2]); w0[3] = f2bf(pv0[3]);
        w1[0] = f2bf(pv1[0]); w1[1] = f2bf(pv1[1]); w1[2] = f2bf(pv1[2]); w1[3] = f2bf(pv1[3]);
        *(u16x4*)&sA[(buf * BM + r0s) * LDK + c4s * 4]      = w0;
        *(u16x4*)&sA[(buf * BM + 32 + r0s) * LDK + c4s * 4] = w1;
    };

    load_chunk(0);
    write_chunk(0);
    __syncthreads();

    for (int t = 0; t < NCHUNK; ++t) {
        const int cur = t & 1;
        if (t + 1 < NCHUNK) load_chunk((t + 1) * BK);   // HBM latency hides under MFMAs
        const unsigned short* sAc = &sA[cur * BM * LDK];
#pragma unroll
        for (int ks = 0; ks < BK; ks += 32) {
            bf16x8 af[4], bfx[4], bcx[4];
#pragma unroll
            for (int mi = 0; mi < 4; ++mi)
                af[mi] = *(const bf16x8*)&sAc[(mi * 16 + fr) * LDK + ks + fg];
            const int kk = t * BK + ks + fg;
#pragma unroll
            for (int ni = 0; ni < 4; ++ni) {
                const int nr = n0 + ni * 16 + fr;
                bfx[ni] = *(const bf16x8*)&wt[(size_t)nr * K_SZ + kk];            // L2 hit
                bcx[ni] = *(const bf16x8*)&wt[(size_t)(H_SZ + nr) * K_SZ + kk];   // L2 hit
            }
#pragma unroll
            for (int mi = 0; mi < 4; ++mi)
#pragma unroll
                for (int ni = 0; ni < 4; ++ni) {
                    accF[mi][ni] = __builtin_amdgcn_mfma_f32_16x16x32_bf16(af[mi], bfx[ni], accF[mi][ni], 0, 0, 0);
                    accC[mi][ni] = __builtin_amdgcn_mfma_f32_16x16x32_bf16(af[mi], bcx[ni], accC[mi][ni], 0, 0, 0);
                }
        }
        if (t + 1 < NCHUNK) write_chunk(cur ^ 1);
        __syncthreads();   // also fences LDS before epilogue reuse on last iter
    }

    // ---- epilogue: per-wave-private LDS slice (no barriers), then pure f32x4 streaming.
    // C/D layout: col = lane&15, row = (lane>>4)*4 + reg  [m89/m91-verified]
    float* ef = eW + wave * 2048;   // [16][64] F slice
    float* ec = ef + 1024;          // [16][64] C slice
    const f32x4 bfv = *(const f32x4*)&b_f[n0 + fr * 4];
    const f32x4 bcv = *(const f32x4*)&b_c[n0 + fr * 4];
    const size_t BH = (size_t)B_SZ * H_SZ;

#pragma unroll 1
    for (int mi = 0; mi < 4; ++mi) {
#pragma unroll
        for (int ni = 0; ni < 4; ++ni)
#pragma unroll
            for (int r = 0; r < 4; ++r) {
                const int ri = g * 4 + r;
                const int cc = ni * 16 + fr;
                ef[ri * 64 + cc] = accF[mi][ni][r];
                ec[ri * 64 + cc] = accC[mi][ni][r];
            }
        // same-wave DS ordering: compiler inserts lgkmcnt wait before reads below
#pragma unroll
        for (int rr = 0; rr < 4; ++rr) {
            const int ri = rr * 4 + g;
            const size_t idx = (size_t)(m0 + mi * 16 + ri) * H_SZ + n0 + fr * 4;
            f32x4 pF = *(const f32x4*)&ef[ri * 64 + fr * 4];
            f32x4 pC = *(const f32x4*)&ec[ri * 64 + fr * 4];
            f32x4 cp = __builtin_nontemporal_load((const f32x4*)&c_prev[idx]);
            f32x4 np = __builtin_nontemporal_load((const f32x4*)&n_prev[idx]);
            f32x4 mp = __builtin_nontemporal_load((const f32x4*)&m_prev[idx]);
            f32x4 ho, co, no, mo;
#pragma unroll
            for (int q = 0; q < 4; ++q) {
                float preF = pF[q] + bfv[q];
                float s    = preF + mp[q];
                float mt   = fmaxf(s, 0.0f);
                float ipv  = __expf(-mt);
                float fpv  = __expf(s - mt);
                float ct   = fpv * cp[q] + ipv * tanh_fast(pC[q] + bcv[q]);
                float ntv  = fpv * np[q] + ipv;
                float htv  = tanh_fast(ct / fmaxf(ntv, 1e-8f));
                ho[q] = htv; co[q] = ct; no[q] = ntv; mo[q] = mt;
            }
            // PLAIN stores: let L2 write-combine into full lines (see note above)
            *(f32x4*)&out[idx]          = ho;
            *(f32x4*)&out[BH + idx]     = co;
            *(f32x4*)&out[2 * BH + idx] = no;
            *(f32x4*)&out[3 * BH + idx] = mo;
        }
    }
}

extern "C" void kernel_launch(void* const* d_in, const int* in_sizes, int n_in,
                              void* d_out, int out_size, void* d_ws, size_t ws_size,
                              hipStream_t stream) {
    const float* x      = (const float*)d_in[0];
    const float* h_prev = (const float*)d_in[1];
    const float* c_prev = (const float*)d_in[2];
    const float* n_prev = (const float*)d_in[3];
    const float* m_prev = (const float*)d_in[4];
    const float* w_f    = (const float*)d_in[5];
    const float* w_c    = (const float*)d_in[6];
    const float* r_f    = (const float*)d_in[7];
    const float* r_c    = (const float*)d_in[8];
    const float* b_f    = (const float*)d_in[9];
    const float* b_c    = (const float*)d_in[10];
    float* out = (float*)d_out;
    unsigned short* wt = (unsigned short*)d_ws;   // 1024*768*2 = 1.5 MiB

    prep_weights<<<(2 * H_SZ * K_SZ) / 256, 256, 0, stream>>>(w_f, w_c, r_f, r_c, wt);
    smgu_kernel<<<B_SZ / BM, 512, 0, stream>>>(
        x, h_prev, c_prev, n_prev, m_prev, b_f, b_c, wt, out);
}

// Round 3
// 1585.256 us; speedup vs baseline: 1.0502x; 1.0491x over previous
//
#include <hip/hip_runtime.h>

#define B_SZ   65536
#define IN_SZ  256
#define H_SZ   512
#define K_SZ   768          // IN + H
#define BM     64           // rows per block; each block does ALL 1024 output cols
#define BK     64
#define LDK    72           // padded LDS K-stride (bf16 elems); 144 B rows, 16B aligned
#define NCHUNK (K_SZ / BK)  // 12
#define SLDN   516          // epilogue slab stride (floats): 516*4 B = 2064 B ≡ 16 mod 128
                            //   -> g-groups land 16 banks apart: 2-way alias = free [m136]

typedef __attribute__((ext_vector_type(4))) float          f32x4;
typedef __attribute__((ext_vector_type(8))) __bf16         bf16x8;
typedef __attribute__((ext_vector_type(4))) unsigned short u16x4;

__device__ __forceinline__ unsigned short f2bf(float f) {
    unsigned u = __float_as_uint(f);
    u += 0x7FFFu + ((u >> 16) & 1u);      // round-to-nearest-even
    return (unsigned short)(u >> 16);
}

__device__ __forceinline__ float tanh_fast(float x) {
    x = fminf(fmaxf(x, -16.0f), 16.0f);
    float e = __expf(2.0f * x);
    return (e - 1.0f) / (e + 1.0f);
}

// Build Wt[1024][768] bf16, k-major: rows 0..511 = f-set cols, 512..1023 = c-set cols.
__global__ void prep_weights(const float* __restrict__ w_f, const float* __restrict__ w_c,
                             const float* __restrict__ r_f, const float* __restrict__ r_c,
                             unsigned short* __restrict__ wt) {
    int id = blockIdx.x * 256 + threadIdx.x;
    int n  = id / K_SZ;
    int k  = id - n * K_SZ;
    int col = n & (H_SZ - 1);
    float v;
    if (n < H_SZ) v = (k < IN_SZ) ? w_f[k * H_SZ + col] : r_f[(k - IN_SZ) * H_SZ + col];
    else          v = (k < IN_SZ) ? w_c[k * H_SZ + col] : r_c[(k - IN_SZ) * H_SZ + col];
    wt[(size_t)n * K_SZ + k] = f2bf(v);
}

// One block = 64 rows x full H (1024 output cols incl. F/C sets). 8 waves.
// K-loop: A staged in LDS (double-buffered, bf16); weights direct from L2.
// Epilogue (round-2 redesign): per 16-row group, stage raw F/C pre-activations
// into block-wide LDS slabs, barrier, then every thread handles a LINEAR chunk:
// f32x4 slab read + f32x4 nt loads of c/n/m + math + 4 fully-sequential f32x4
// stores (1 KB contiguous per wave instruction). This removes the round-1
// epilogue's register-pressure spike (12 hoisted nt loads + 4x4 outputs live)
// and makes the write pattern definitionally coalesced — targeting the 7.5x
// WRITE_SIZE amplification (3.94 GB vs 537 MB ideal) seen in rounds 1-2.
__launch_bounds__(512, 2)
__global__ void smgu_kernel(const float* __restrict__ x, const float* __restrict__ h_prev,
                            const float* __restrict__ c_prev, const float* __restrict__ n_prev,
                            const float* __restrict__ m_prev,
                            const float* __restrict__ b_f, const float* __restrict__ b_c,
                            const unsigned short* __restrict__ wt,
                            float* __restrict__ out) {
    // union: K-loop uses sA [2][BM][LDK] bf16 = 18432 B;
    //        epilogue uses 2 slabs of [16][SLDN] f32 = 66048 B
    __shared__ __align__(16) unsigned char smem[2 * 16 * SLDN * 4];
    unsigned short* sA    = (unsigned short*)smem;
    float*          slabF = (float*)smem;
    float*          slabC = slabF + 16 * SLDN;

    const int tid  = threadIdx.x;
    const int m0   = blockIdx.x * BM;
    const int lane = tid & 63;
    const int wave = tid >> 6;            // 0..7 -> H-col group
    const int n0   = wave * 64;
    const int fr   = lane & 15;
    const int fg   = (lane >> 4) * 8;     // k-octet offset
    const int g    = lane >> 4;

    f32x4 accF[4][4], accC[4][4];
#pragma unroll
    for (int i = 0; i < 4; ++i)
#pragma unroll
        for (int j = 0; j < 4; ++j) { accF[i][j] = (f32x4)0.0f; accC[i][j] = (f32x4)0.0f; }

    // staging map: 1024 float4 chunks (64 rows x 16), thread does chunks tid and tid+512
    const int r0s = tid >> 4;             // 0..31
    const int c4s = tid & 15;

    f32x4 pv0, pv1;
    auto load_chunk = [&](int kb) {
        const float* src; int ld, kl;
        if (kb < IN_SZ) { src = x;      ld = IN_SZ; kl = kb; }
        else            { src = h_prev; ld = H_SZ;  kl = kb - IN_SZ; }
        pv0 = __builtin_nontemporal_load(
            (const f32x4*)&src[(size_t)(m0 + r0s) * ld + kl + c4s * 4]);
        pv1 = __builtin_nontemporal_load(
            (const f32x4*)&src[(size_t)(m0 + 32 + r0s) * ld + kl + c4s * 4]);
    };
    auto write_chunk = [&](int buf) {
        u16x4 w0, w1;
        w0[0] = f2bf(pv0[0]); w0[1] = f2bf(pv0[1]); w0[2] = f2bf(pv0[2]); w0[3] = f2bf(pv0[3]);
        w1[0] = f2bf(pv1[0]); w1[1] = f2bf(pv1[1]); w1[2] = f2bf(pv1[2]); w1[3] = f2bf(pv1[3]);
        *(u16x4*)&sA[(buf * BM + r0s) * LDK + c4s * 4]      = w0;
        *(u16x4*)&sA[(buf * BM + 32 + r0s) * LDK + c4s * 4] = w1;
    };

    load_chunk(0);
    write_chunk(0);
    __syncthreads();

    for (int t = 0; t < NCHUNK; ++t) {
        const int cur = t & 1;
        if (t + 1 < NCHUNK) load_chunk((t + 1) * BK);   // HBM latency hides under MFMAs
        const unsigned short* sAc = &sA[cur * BM * LDK];
#pragma unroll
        for (int ks = 0; ks < BK; ks += 32) {
            bf16x8 af[4], bfx[4], bcx[4];
#pragma unroll
            for (int mi = 0; mi < 4; ++mi)
                af[mi] = *(const bf16x8*)&sAc[(mi * 16 + fr) * LDK + ks + fg];
            const int kk = t * BK + ks + fg;
#pragma unroll
            for (int ni = 0; ni < 4; ++ni) {
                const int nr = n0 + ni * 16 + fr;
                bfx[ni] = *(const bf16x8*)&wt[(size_t)nr * K_SZ + kk];            // L2 hit
                bcx[ni] = *(const bf16x8*)&wt[(size_t)(H_SZ + nr) * K_SZ + kk];   // L2 hit
            }
#pragma unroll
            for (int mi = 0; mi < 4; ++mi)
#pragma unroll
                for (int ni = 0; ni < 4; ++ni) {
                    accF[mi][ni] = __builtin_amdgcn_mfma_f32_16x16x32_bf16(af[mi], bfx[ni], accF[mi][ni], 0, 0, 0);
                    accC[mi][ni] = __builtin_amdgcn_mfma_f32_16x16x32_bf16(af[mi], bcx[ni], accC[mi][ni], 0, 0, 0);
                }
        }
        if (t + 1 < NCHUNK) write_chunk(cur ^ 1);
        __syncthreads();   // final iter: fences LDS before epilogue slab reuse
    }

    // ---- epilogue: block-linear via LDS slab exchange.
    // MFMA C/D layout: col = ni*16 + (lane&15), row = (lane>>4)*4 + reg  [m89/m91]
    const size_t BH = (size_t)B_SZ * H_SZ;

#pragma unroll 1
    for (int mi = 0; mi < 4; ++mi) {
        // stage raw pre-activations for these 16 rows x 512 cols
#pragma unroll
        for (int ni = 0; ni < 4; ++ni)
#pragma unroll
            for (int r = 0; r < 4; ++r) {
                const int rl = g * 4 + r;
                const int cc = n0 + ni * 16 + fr;
                slabF[rl * SLDN + cc] = accF[mi][ni][r];
                slabC[rl * SLDN + cc] = accC[mi][ni][r];
            }
        __syncthreads();

        // linear pass: 16 rows x 512 cols = 2048 f32x4 chunks; 4 per thread
#pragma unroll
        for (int j = 0; j < 4; ++j) {
            const int flat = tid + 512 * j;
            const int row  = flat >> 7;          // 0..15
            const int c4   = flat & 127;         // f32x4 column index
            const size_t idx = (size_t)(m0 + mi * 16 + row) * H_SZ + c4 * 4;
            f32x4 pF = *(const f32x4*)&slabF[row * SLDN + c4 * 4];
            f32x4 pC = *(const f32x4*)&slabC[row * SLDN + c4 * 4];
            f32x4 bfv = *(const f32x4*)&b_f[c4 * 4];
            f32x4 bcv = *(const f32x4*)&b_c[c4 * 4];
            f32x4 cp = __builtin_nontemporal_load((const f32x4*)&c_prev[idx]);
            f32x4 np = __builtin_nontemporal_load((const f32x4*)&n_prev[idx]);
            f32x4 mp = __builtin_nontemporal_load((const f32x4*)&m_prev[idx]);
            f32x4 ho, co, no, mo;
#pragma unroll
            for (int q = 0; q < 4; ++q) {
                float preF = pF[q] + bfv[q];
                float s    = preF + mp[q];
                float mt   = fmaxf(s, 0.0f);
                float ipv  = __expf(-mt);
                float fpv  = __expf(s - mt);
                float ct   = fpv * cp[q] + ipv * tanh_fast(pC[q] + bcv[q]);
                float ntv  = fpv * np[q] + ipv;
                float htv  = tanh_fast(ct / fmaxf(ntv, 1e-8f));
                ho[q] = htv; co[q] = ct; no[q] = ntv; mo[q] = mt;
            }
            *(f32x4*)&out[idx]          = ho;
            *(f32x4*)&out[BH + idx]     = co;
            *(f32x4*)&out[2 * BH + idx] = no;
            *(f32x4*)&out[3 * BH + idx] = mo;
        }
        __syncthreads();   // slabs reused next mi
    }
}

extern "C" void kernel_launch(void* const* d_in, const int* in_sizes, int n_in,
                              void* d_out, int out_size, void* d_ws, size_t ws_size,
                              hipStream_t stream) {
    const float* x      = (const float*)d_in[0];
    const float* h_prev = (const float*)d_in[1];
    const float* c_prev = (const float*)d_in[2];
    const float* n_prev = (const float*)d_in[3];
    const float* m_prev = (const float*)d_in[4];
    const float* w_f    = (const float*)d_in[5];
    const float* w_c    = (const float*)d_in[6];
    const float* r_f    = (const float*)d_in[7];
    const float* r_c    = (const float*)d_in[8];
    const float* b_f    = (const float*)d_in[9];
    const float* b_c    = (const float*)d_in[10];
    float* out = (float*)d_out;
    unsigned short* wt = (unsigned short*)d_ws;   // 1024*768*2 = 1.5 MiB

    prep_weights<<<(2 * H_SZ * K_SZ) / 256, 256, 0, stream>>>(w_f, w_c, r_f, r_c, wt);
    smgu_kernel<<<B_SZ / BM, 512, 0, stream>>>(
        x, h_prev, c_prev, n_prev, m_prev, b_f, b_c, wt, out);
}